// Round 5
// baseline (5159.619 us; speedup 1.0000x reference)
//
#include <hip/hip_runtime.h>
#include <math.h>

#define NN 100000
#define EE 1600000
#define CCH 32
#define NC (NN*CCH)
#define ET (EE+NN)          // edges + self loops (one per node)
#define NEGS 0.01f
#define GNEG 0.2f
#define BEPS 1e-5f

// ============ CSR build ============

__global__ void k_degs(const int* __restrict__ src, const int* __restrict__ dst,
                       float* __restrict__ deg_out, int* __restrict__ indeg){
    int e = blockIdx.x*blockDim.x + threadIdx.x;
    if (e >= EE) return;
    atomicAdd(&deg_out[src[e]], 1.0f);
    atomicAdd(&indeg[dst[e]], 1);
}

#define SCAN_T 1024
__global__ void k_scan(const int* __restrict__ indeg, int* __restrict__ row){
    __shared__ int sdata[SCAN_T];
    int t = threadIdx.x;
    const int per = (NN + SCAN_T - 1)/SCAN_T;
    int lo = t*per, hi = (lo + per < NN) ? lo + per : NN;
    int s = 0;
    for (int d = lo; d < hi; d++) s += indeg[d] + 1;
    sdata[t] = s;
    __syncthreads();
    for (int off = 1; off < SCAN_T; off <<= 1){
        int v = (t >= off) ? sdata[t-off] : 0;
        __syncthreads();
        sdata[t] += v;
        __syncthreads();
    }
    int excl = (t == 0) ? 0 : sdata[t-1];
    for (int d = lo; d < hi; d++){
        row[d] = excl;
        excl += indeg[d] + 1;
    }
    if (t == 0) row[NN] = ET;
}

__global__ void k_self(const int* __restrict__ row, int* __restrict__ csr_src,
                       float* __restrict__ csr_w){
    int d = blockIdx.x*blockDim.x + threadIdx.x;
    if (d >= NN) return;
    int p = row[d];
    csr_src[p] = d;
    csr_w[p] = 0.0f;
}

__global__ void k_scatter(const int* __restrict__ src, const int* __restrict__ dst,
                          const float* __restrict__ deg_out, const int* __restrict__ row,
                          int* __restrict__ cur, int* __restrict__ csr_src,
                          float* __restrict__ csr_w){
    int e = blockIdx.x*blockDim.x + threadIdx.x;
    if (e >= EE) return;
    int s = src[e], d = dst[e];
    int pos = row[d] + 1 + atomicAdd(&cur[d], 1);
    csr_src[pos] = s;
    float di = deg_out[s] * deg_out[d];
    csr_w[pos] = (di > 0.0f) ? (-1.0f / sqrtf(fmaxf(di, 1e-12f))) : 0.0f;
}

// ============ gather SpMV: float2 channels, 4 edge-slots/wave, unroll x2 ============
__global__ void k_spmv_csr(const int* __restrict__ row, const int* __restrict__ csr_src,
                           const float* __restrict__ csr_w, const float* __restrict__ v,
                           const float* __restrict__ tprev, float* __restrict__ out, int first){
    int gid = blockIdx.x*blockDim.x + threadIdx.x;
    int node = gid >> 6;
    if (node >= NN) return;
    int lane = gid & 63;
    int slot = lane >> 4;       // 0..3
    int l = lane & 15;          // channel pair index
    const float2* V2 = (const float2*)v;
    int start = row[node] + 1, end = row[node+1];   // skip self-loop slot
    float2 acc = {0.0f, 0.0f};
    int p = start + slot;
    for (; p + 4 < end; p += 8){
        int s0 = csr_src[p], s1 = csr_src[p+4];
        float w0 = csr_w[p], w1 = csr_w[p+4];
        float2 v0 = V2[(size_t)s0*16 + l];
        float2 v1 = V2[(size_t)s1*16 + l];
        acc.x += w0*v0.x + w1*v1.x;
        acc.y += w0*v0.y + w1*v1.y;
    }
    if (p < end){
        float w0 = csr_w[p];
        float2 v0 = V2[(size_t)csr_src[p]*16 + l];
        acc.x += w0*v0.x;
        acc.y += w0*v0.y;
    }
    acc.x += __shfl_xor(acc.x, 32); acc.y += __shfl_xor(acc.y, 32);
    acc.x += __shfl_xor(acc.x, 16); acc.y += __shfl_xor(acc.y, 16);
    if (slot == 0){
        float2 r;
        if (first){
            r = acc;
        } else {
            float2 t = ((const float2*)tprev)[(size_t)node*16 + l];
            r.x = 2.0f*acc.x - t.x;
            r.y = 2.0f*acc.y - t.y;
        }
        ((float2*)out)[(size_t)node*16 + l] = r;
    }
}

// ============ Wg_k = W_k @ G, cbg = cb @ G (tiny) ============
__global__ void k_wg(const float* __restrict__ W, const float* __restrict__ cb,
                     const float* __restrict__ G, float* __restrict__ Wg,
                     float* __restrict__ cbg, int K){
    int t = blockIdx.x*blockDim.x + threadIdx.x;
    if (t < K*2048){
        int k = t >> 11, r = t & 2047;
        int i = r >> 6, j = r & 63;
        float s = 0.0f;
        #pragma unroll 8
        for (int q = 0; q < 32; q++) s += W[k*1024 + i*32 + q] * G[q*64 + j];
        Wg[t] = s;
    } else if (t < K*2048 + 64){
        int j = t - K*2048;
        float s = 0.0f;
        #pragma unroll 8
        for (int q = 0; q < 32; q++) s += cb[q] * G[q*64 + j];
        cbg[j] = s;
    }
}

// ============ H = (sum_k T_k @ Wg_k) + cbg; also attL/attR dots ============
__global__ void k_hfused(const float* __restrict__ T0, const float* __restrict__ T1,
                         const float* __restrict__ T2, const float* __restrict__ T3,
                         const float* __restrict__ T4,
                         const float* __restrict__ Wg, const float* __restrict__ cbg,
                         const float* __restrict__ al, const float* __restrict__ ar,
                         int K, float* __restrict__ Hh,
                         float* __restrict__ attL, float* __restrict__ attR){
    __shared__ float sW[5*2048];
    for (int i = threadIdx.x; i < K*2048; i += blockDim.x) sW[i] = Wg[i];
    __syncthreads();
    int gid = blockIdx.x*blockDim.x + threadIdx.x;
    int node = gid >> 6;
    if (node >= NN) return;
    int lane = gid & 63;
    int h = lane >> 5, c = lane & 31;
    const float* Ts[5] = {T0, T1, T2, T3, T4};
    float acc = cbg[lane];
    for (int k = 0; k < K; k++){
        float tv = Ts[k][(size_t)node*CCH + c];
        const float* wrow = &sW[k*2048];
        #pragma unroll
        for (int i = 0; i < 32; i++){
            float t = __shfl(tv, i);
            acc += t * wrow[i*64 + lane];
        }
    }
    Hh[(size_t)node*64 + lane] = acc;
    float va = acc * al[lane];
    float vr = acc * ar[lane];
    #pragma unroll
    for (int m = 16; m >= 1; m >>= 1){
        va += __shfl_xor(va, m);
        vr += __shfl_xor(vr, m);
    }
    if (c == 0){
        attL[(size_t)node*2 + h] = va;
        attR[(size_t)node*2 + h] = vr;
    }
}

// ============ fused SuperGAT, single pass, float2 lanes, 2 edge-slots/wave ============
// lane = slot(1b) | head(1b) | chanpair(4b); block = 512 (8 waves)
__global__ void k_gat(const int* __restrict__ row, const int* __restrict__ csr_src,
                      const float* __restrict__ Hh,
                      const float* __restrict__ attL, const float* __restrict__ attR,
                      const float* __restrict__ gb,
                      float* __restrict__ y, float* __restrict__ sums){
    int gid = blockIdx.x*blockDim.x + threadIdx.x;
    int node = gid >> 6;
    int lane = gid & 63;
    int wv_ = threadIdx.x >> 6;
    int slot = lane >> 5;
    int l = lane & 31;
    int h = l >> 4;
    __shared__ float2 s_sum[8*16], s_sq[8*16];
    float2 yv = {0.0f, 0.0f};
    if (node < NN){
        const float2* H2 = (const float2*)Hh;
        float2 hi = H2[(size_t)node*32 + l];
        float ai = attR[(size_t)node*2 + h];
        int start = row[node], end = row[node+1];
        float m = -1e30f, den = 0.0f;
        float2 acc = {0.0f, 0.0f};
        int p = start + slot;
        for (; p + 2 < end; p += 4){
            int s0 = csr_src[p], s1 = csr_src[p+2];
            float2 hj0 = H2[(size_t)s0*32 + l];
            float2 hj1 = H2[(size_t)s1*32 + l];
            float aL0 = attL[(size_t)s0*2 + h];
            float aL1 = attL[(size_t)s1*2 + h];
            float lg0 = hi.x*hj0.x + hi.y*hj0.y;
            float lg1 = hi.x*hj1.x + hi.y*hj1.y;
            #pragma unroll
            for (int mm = 8; mm >= 1; mm >>= 1){
                lg0 += __shfl_xor(lg0, mm);
                lg1 += __shfl_xor(lg1, mm);
            }
            float a0 = (aL0 + ai) / (1.0f + __expf(-lg0));
            float a1 = (aL1 + ai) / (1.0f + __expf(-lg1));
            a0 = (a0 > 0.0f) ? a0 : GNEG*a0;
            a1 = (a1 > 0.0f) ? a1 : GNEG*a1;
            float mn = fmaxf(fmaxf(m, a0), a1);
            float sc = __expf(m - mn);
            float w0 = __expf(a0 - mn);
            float w1 = __expf(a1 - mn);
            den = den*sc + w0 + w1;
            acc.x = acc.x*sc + w0*hj0.x + w1*hj1.x;
            acc.y = acc.y*sc + w0*hj0.y + w1*hj1.y;
            m = mn;
        }
        for (; p < end; p += 2){
            int s0 = csr_src[p];
            float2 hj0 = H2[(size_t)s0*32 + l];
            float aL0 = attL[(size_t)s0*2 + h];
            float lg0 = hi.x*hj0.x + hi.y*hj0.y;
            #pragma unroll
            for (int mm = 8; mm >= 1; mm >>= 1) lg0 += __shfl_xor(lg0, mm);
            float a0 = (aL0 + ai) / (1.0f + __expf(-lg0));
            a0 = (a0 > 0.0f) ? a0 : GNEG*a0;
            float mn = fmaxf(m, a0);
            float sc = __expf(m - mn);
            float w0 = __expf(a0 - mn);
            den = den*sc + w0;
            acc.x = acc.x*sc + w0*hj0.x;
            acc.y = acc.y*sc + w0*hj0.y;
            m = mn;
        }
        // merge the two edge-slots (online-softmax merge across lane^32)
        float mo  = __shfl_xor(m, 32);
        float dno = __shfl_xor(den, 32);
        float aox = __shfl_xor(acc.x, 32);
        float aoy = __shfl_xor(acc.y, 32);
        float mt = fmaxf(m, mo);
        float sA = __expf(m - mt), sB = __expf(mo - mt);
        float dent = den*sA + dno*sB + 1e-16f;
        float accx = (acc.x*sA + aox*sB) / dent;
        float accy = (acc.y*sA + aoy*sB) / dent;
        // head mean (lane^16)
        float hx = __shfl_xor(accx, 16);
        float hy = __shfl_xor(accy, 16);
        float2 g = ((const float2*)gb)[l & 15];
        float sx = 0.5f*(accx + hx) + g.x;
        float sy = 0.5f*(accy + hy) + g.y;
        yv.x = (sx > 0.0f) ? 2.0f*sx : (1.0f + NEGS)*sx;   // leaky(s)+s
        yv.y = (sy > 0.0f) ? 2.0f*sy : (1.0f + NEGS)*sy;
        if (lane < 16) ((float2*)y)[(size_t)node*16 + l] = yv;
    }
    if (lane < 16){
        s_sum[wv_*16 + l] = yv;
        float2 q = {yv.x*yv.x, yv.y*yv.y};
        s_sq[wv_*16 + l] = q;
    }
    __syncthreads();
    if (threadIdx.x < 16){
        float2 s = {0.0f,0.0f}, q = {0.0f,0.0f};
        #pragma unroll
        for (int r = 0; r < 8; r++){
            float2 a = s_sum[r*16 + threadIdx.x];
            float2 b = s_sq[r*16 + threadIdx.x];
            s.x += a.x; s.y += a.y;
            q.x += b.x; q.y += b.y;
        }
        atomicAdd(&sums[2*threadIdx.x],      s.x);
        atomicAdd(&sums[2*threadIdx.x + 1],  s.y);
        atomicAdd(&sums[32 + 2*threadIdx.x], q.x);
        atomicAdd(&sums[33 + 2*threadIdx.x], q.y);
    }
}

// ============ BN normalize + accumulate (0 store, 1 add, 2 add+final leaky) ============
__global__ void k_norm(const float* __restrict__ y, const float* __restrict__ sums,
                       const float* __restrict__ gm, const float* __restrict__ bt,
                       float* __restrict__ acc, int mode){
    int t = blockIdx.x*blockDim.x + threadIdx.x;
    if (t >= NC) return;
    int c = t & 31;
    const float invN = 1.0f / (float)NN;
    float mu = sums[c] * invN;
    float var = sums[32 + c] * invN - mu*mu;
    float inv = 1.0f / sqrtf(var + BEPS);
    float v = gm[c] * (y[t] - mu) * inv + bt[c];
    if (mode == 0){
        acc[t] = v;
    } else if (mode == 1){
        acc[t] += v;
    } else {
        float a = acc[t] + v;
        acc[t] = (a > 0.0f) ? a : NEGS*a;
    }
}

extern "C" void kernel_launch(void* const* d_in, const int* in_sizes, int n_in,
                              void* d_out, int out_size, void* d_ws, size_t ws_size,
                              hipStream_t stream){
    const float* x   = (const float*)d_in[0];
    const int*   ei  = (const int*)d_in[1];
    const int*   src = ei;
    const int*   dst = ei + EE;

    const float *Wp[4], *cbp[4], *Gp[4], *alp[4], *arp[4], *gbp[4], *gmp[4], *btp[4];
    for (int b = 0; b < 4; b++){
        int base = 3 + 8*b;
        Wp[b]  = (const float*)d_in[base+0];
        cbp[b] = (const float*)d_in[base+1];
        Gp[b]  = (const float*)d_in[base+2];
        alp[b] = (const float*)d_in[base+3];
        arp[b] = (const float*)d_in[base+4];
        gbp[b] = (const float*)d_in[base+5];
        gmp[b] = (const float*)d_in[base+6];
        btp[b] = (const float*)d_in[base+7];
    }

    // 16B-aligned workspace carve-up (float2 stores require 8B+ alignment)
    char* w8 = (char*)d_ws;
    #define CARVE(ptr_t, name, bytes) ptr_t name = (ptr_t)w8; w8 += (((size_t)(bytes)) + 15) & ~(size_t)15;
    CARVE(float*, deg_out, sizeof(float)*NN)
    CARVE(int*,   indeg,   sizeof(int)*NN)
    CARVE(int*,   cur,     sizeof(int)*NN)
    CARVE(int*,   row,     sizeof(int)*(NN+1))
    CARVE(int*,   csr_src, sizeof(int)*ET)
    CARVE(float*, csr_w,   sizeof(float)*ET)
    CARVE(float*, T1,      sizeof(float)*NC)
    CARVE(float*, T2,      sizeof(float)*NC)
    CARVE(float*, T3,      sizeof(float)*NC)
    CARVE(float*, T4,      sizeof(float)*NC)
    CARVE(float*, Hh,      sizeof(float)*2*NC)
    CARVE(float*, attL,    sizeof(float)*2*NN)
    CARVE(float*, attR,    sizeof(float)*2*NN)
    CARVE(float*, yb,      sizeof(float)*NC)
    CARVE(float*, Wg,      sizeof(float)*4*5*2048)
    CARVE(float*, cbg,     sizeof(float)*4*64)
    CARVE(float*, sums,    sizeof(float)*64)

    float* acc = (float*)d_out;

    const int B = 256;
    const int gE  = (EE + B - 1)/B;
    const int gN  = (NN + B - 1)/B;
    const int gNC = (NC + B - 1)/B;
    const int gW  = (NN*64 + B - 1)/B;      // one-wave-per-node @256
    const int gW5 = (NN*64 + 511)/512;      // one-wave-per-node @512

    // ---- CSR build ----
    hipMemsetAsync(deg_out, 0, (size_t)3*NN*sizeof(int), stream);  // deg_out, indeg, cur
    k_degs<<<gE, B, 0, stream>>>(src, dst, deg_out, indeg);
    k_scan<<<1, SCAN_T, 0, stream>>>(indeg, row);
    k_self<<<gN, B, 0, stream>>>(row, csr_src, csr_w);
    k_scatter<<<gE, B, 0, stream>>>(src, dst, deg_out, row, cur, csr_src, csr_w);

    // ---- shared Chebyshev basis ----
    k_spmv_csr<<<gW5, 512, 0, stream>>>(row, csr_src, csr_w, x,  (const float*)0, T1, 1);
    k_spmv_csr<<<gW5, 512, 0, stream>>>(row, csr_src, csr_w, T1, x,  T2, 0);
    k_spmv_csr<<<gW5, 512, 0, stream>>>(row, csr_src, csr_w, T2, T1, T3, 0);
    k_spmv_csr<<<gW5, 512, 0, stream>>>(row, csr_src, csr_w, T3, T2, T4, 0);

    // ---- per-block folded weights ----
    const int Ks[4] = {3, 3, 5, 5};
    for (int b = 0; b < 4; b++){
        int tot = Ks[b]*2048 + 64;
        k_wg<<<(tot + B - 1)/B, B, 0, stream>>>(Wp[b], cbp[b], Gp[b],
                                                Wg + b*5*2048, cbg + b*64, Ks[b]);
    }

    // ---- per-block pipeline ----
    for (int b = 0; b < 4; b++){
        k_hfused<<<gW, B, 0, stream>>>(x, T1, T2, T3, T4, Wg + b*5*2048, cbg + b*64,
                                       alp[b], arp[b], Ks[b], Hh, attL, attR);
        hipMemsetAsync(sums, 0, 64*sizeof(float), stream);
        k_gat<<<gW5, 512, 0, stream>>>(row, csr_src, Hh, attL, attR, gbp[b],
                                       yb, sums);
        int mode = (b == 0) ? 0 : ((b == 3) ? 2 : 1);
        k_norm<<<gNC, B, 0, stream>>>(yb, sums, gmp[b], btp[b], acc, mode);
    }
}

// Round 6
// 3298.762 us; speedup vs baseline: 1.5641x; 1.5641x over previous
//
#include <hip/hip_runtime.h>
#include <math.h>

#define NN 100000
#define EE 1600000
#define CCH 32
#define NC (NN*CCH)
#define ET (EE+NN)          // edges + self loops (one per node)
#define NEGS 0.01f
#define GNEG 0.2f
#define BEPS 1e-5f

// ============ CSR build ============

__global__ void k_degs(const int* __restrict__ src, const int* __restrict__ dst,
                       float* __restrict__ deg_out, int* __restrict__ indeg){
    int e = blockIdx.x*blockDim.x + threadIdx.x;
    if (e >= EE) return;
    atomicAdd(&deg_out[src[e]], 1.0f);
    atomicAdd(&indeg[dst[e]], 1);
}

#define SCAN_T 1024
__global__ void k_scan(const int* __restrict__ indeg, int* __restrict__ row){
    __shared__ int sdata[SCAN_T];
    int t = threadIdx.x;
    const int per = (NN + SCAN_T - 1)/SCAN_T;
    int lo = t*per, hi = (lo + per < NN) ? lo + per : NN;
    int s = 0;
    for (int d = lo; d < hi; d++) s += indeg[d] + 1;
    sdata[t] = s;
    __syncthreads();
    for (int off = 1; off < SCAN_T; off <<= 1){
        int v = (t >= off) ? sdata[t-off] : 0;
        __syncthreads();
        sdata[t] += v;
        __syncthreads();
    }
    int excl = (t == 0) ? 0 : sdata[t-1];
    for (int d = lo; d < hi; d++){
        row[d] = excl;
        excl += indeg[d] + 1;
    }
    if (t == 0) row[NN] = ET;
}

__global__ void k_self(const int* __restrict__ row, int* __restrict__ csr_src,
                       float* __restrict__ csr_w){
    int d = blockIdx.x*blockDim.x + threadIdx.x;
    if (d >= NN) return;
    int p = row[d];
    csr_src[p] = d;
    csr_w[p] = 0.0f;
}

__global__ void k_scatter(const int* __restrict__ src, const int* __restrict__ dst,
                          const float* __restrict__ deg_out, const int* __restrict__ row,
                          int* __restrict__ cur, int* __restrict__ csr_src,
                          float* __restrict__ csr_w){
    int e = blockIdx.x*blockDim.x + threadIdx.x;
    if (e >= EE) return;
    int s = src[e], d = dst[e];
    int pos = row[d] + 1 + atomicAdd(&cur[d], 1);
    csr_src[pos] = s;
    float di = deg_out[s] * deg_out[d];
    csr_w[pos] = (di > 0.0f) ? (-1.0f / sqrtf(fmaxf(di, 1e-12f))) : 0.0f;
}

// ============ gather SpMV: float2 channels, 4 edge-slots/wave, unroll x2 ============
__global__ void k_spmv_csr(const int* __restrict__ row, const int* __restrict__ csr_src,
                           const float* __restrict__ csr_w, const float* __restrict__ v,
                           const float* __restrict__ tprev, float* __restrict__ out, int first){
    int gid = blockIdx.x*blockDim.x + threadIdx.x;
    int node = gid >> 6;
    if (node >= NN) return;
    int lane = gid & 63;
    int slot = lane >> 4;       // 0..3
    int l = lane & 15;          // channel pair index
    const float2* V2 = (const float2*)v;
    int start = row[node] + 1, end = row[node+1];   // skip self-loop slot
    float2 acc = {0.0f, 0.0f};
    int p = start + slot;
    for (; p + 4 < end; p += 8){
        int s0 = csr_src[p], s1 = csr_src[p+4];
        float w0 = csr_w[p], w1 = csr_w[p+4];
        float2 v0 = V2[(size_t)s0*16 + l];
        float2 v1 = V2[(size_t)s1*16 + l];
        acc.x += w0*v0.x + w1*v1.x;
        acc.y += w0*v0.y + w1*v1.y;
    }
    if (p < end){
        float w0 = csr_w[p];
        float2 v0 = V2[(size_t)csr_src[p]*16 + l];
        acc.x += w0*v0.x;
        acc.y += w0*v0.y;
    }
    acc.x += __shfl_xor(acc.x, 32); acc.y += __shfl_xor(acc.y, 32);
    acc.x += __shfl_xor(acc.x, 16); acc.y += __shfl_xor(acc.y, 16);
    if (slot == 0){
        float2 r;
        if (first){
            r = acc;
        } else {
            float2 t = ((const float2*)tprev)[(size_t)node*16 + l];
            r.x = 2.0f*acc.x - t.x;
            r.y = 2.0f*acc.y - t.y;
        }
        ((float2*)out)[(size_t)node*16 + l] = r;
    }
}

// ============ Wg_k = W_k @ G, cbg = cb @ G (tiny) ============
__global__ void k_wg(const float* __restrict__ W, const float* __restrict__ cb,
                     const float* __restrict__ G, float* __restrict__ Wg,
                     float* __restrict__ cbg, int K){
    int t = blockIdx.x*blockDim.x + threadIdx.x;
    if (t < K*2048){
        int k = t >> 11, r = t & 2047;
        int i = r >> 6, j = r & 63;
        float s = 0.0f;
        #pragma unroll 8
        for (int q = 0; q < 32; q++) s += W[k*1024 + i*32 + q] * G[q*64 + j];
        Wg[t] = s;
    } else if (t < K*2048 + 64){
        int j = t - K*2048;
        float s = 0.0f;
        #pragma unroll 8
        for (int q = 0; q < 32; q++) s += cb[q] * G[q*64 + j];
        cbg[j] = s;
    }
}

// ============ H = (sum_k T_k @ Wg_k) + cbg; also attL/attR dots ============
// 512 threads/block: 4 blocks x 40KB LDS = 160KB/CU -> full 32-wave occupancy
__global__ void k_hfused(const float* __restrict__ T0, const float* __restrict__ T1,
                         const float* __restrict__ T2, const float* __restrict__ T3,
                         const float* __restrict__ T4,
                         const float* __restrict__ Wg, const float* __restrict__ cbg,
                         const float* __restrict__ al, const float* __restrict__ ar,
                         int K, float* __restrict__ Hh,
                         float* __restrict__ attL, float* __restrict__ attR){
    __shared__ float sW[5*2048];
    for (int i = threadIdx.x; i < K*2048; i += blockDim.x) sW[i] = Wg[i];
    __syncthreads();
    int gid = blockIdx.x*blockDim.x + threadIdx.x;
    int node = gid >> 6;
    if (node >= NN) return;
    int lane = gid & 63;
    int h = lane >> 5, c = lane & 31;
    const float* Ts[5] = {T0, T1, T2, T3, T4};
    float acc = cbg[lane];
    for (int k = 0; k < K; k++){
        float tv = Ts[k][(size_t)node*CCH + c];
        const float* wrow = &sW[k*2048];
        #pragma unroll
        for (int i = 0; i < 32; i++){
            float t = __shfl(tv, i);
            acc += t * wrow[i*64 + lane];
        }
    }
    Hh[(size_t)node*64 + lane] = acc;
    float va = acc * al[lane];
    float vr = acc * ar[lane];
    #pragma unroll
    for (int m = 16; m >= 1; m >>= 1){
        va += __shfl_xor(va, m);
        vr += __shfl_xor(vr, m);
    }
    if (c == 0){
        attL[(size_t)node*2 + h] = va;
        attR[(size_t)node*2 + h] = vr;
    }
}

// ============ fused SuperGAT, single pass (online softmax), unroll x4 ============
// one wave per dst node: 64 lanes = 2 heads x 32 channels; 4 interleaved shfl chains
__global__ void k_gat(const int* __restrict__ row, const int* __restrict__ csr_src,
                      const float* __restrict__ Hh,
                      const float* __restrict__ attL, const float* __restrict__ attR,
                      const float* __restrict__ gb,
                      float* __restrict__ y, float* __restrict__ sums){
    int gid = blockIdx.x*blockDim.x + threadIdx.x;
    int node = gid >> 6;
    int lane = gid & 63;
    int wv_ = threadIdx.x >> 6;
    int h = lane >> 5, c = lane & 31;
    __shared__ float ssum[8*32], ssq[8*32];
    float yv = 0.0f;
    if (node < NN){
        float hi = Hh[(size_t)node*64 + lane];
        float ai = attR[(size_t)node*2 + h];
        int start = row[node], end = row[node+1];
        float m = -1e30f, den = 0.0f, acc = 0.0f;
        int p = start;
        for (; p + 3 < end; p += 4){
            int s0 = csr_src[p], s1 = csr_src[p+1];
            int s2 = csr_src[p+2], s3 = csr_src[p+3];
            float hj0 = Hh[(size_t)s0*64 + lane];
            float hj1 = Hh[(size_t)s1*64 + lane];
            float hj2 = Hh[(size_t)s2*64 + lane];
            float hj3 = Hh[(size_t)s3*64 + lane];
            float aL0 = attL[(size_t)s0*2 + h];
            float aL1 = attL[(size_t)s1*2 + h];
            float aL2 = attL[(size_t)s2*2 + h];
            float aL3 = attL[(size_t)s3*2 + h];
            float lg0 = hi*hj0, lg1 = hi*hj1, lg2 = hi*hj2, lg3 = hi*hj3;
            #pragma unroll
            for (int mm = 16; mm >= 1; mm >>= 1){
                lg0 += __shfl_xor(lg0, mm);
                lg1 += __shfl_xor(lg1, mm);
                lg2 += __shfl_xor(lg2, mm);
                lg3 += __shfl_xor(lg3, mm);
            }
            float a0 = (aL0 + ai) / (1.0f + __expf(-lg0));
            float a1 = (aL1 + ai) / (1.0f + __expf(-lg1));
            float a2 = (aL2 + ai) / (1.0f + __expf(-lg2));
            float a3 = (aL3 + ai) / (1.0f + __expf(-lg3));
            a0 = (a0 > 0.0f) ? a0 : GNEG*a0;
            a1 = (a1 > 0.0f) ? a1 : GNEG*a1;
            a2 = (a2 > 0.0f) ? a2 : GNEG*a2;
            a3 = (a3 > 0.0f) ? a3 : GNEG*a3;
            float mn = fmaxf(fmaxf(m, fmaxf(a0, a1)), fmaxf(a2, a3));  // max3 tree
            float sc = __expf(m - mn);
            float w0 = __expf(a0 - mn);
            float w1 = __expf(a1 - mn);
            float w2 = __expf(a2 - mn);
            float w3 = __expf(a3 - mn);
            den = den*sc + ((w0 + w1) + (w2 + w3));
            acc = acc*sc + (w0*hj0 + w1*hj1) + (w2*hj2 + w3*hj3);
            m = mn;
        }
        for (; p < end; p++){
            int s0 = csr_src[p];
            float hj0 = Hh[(size_t)s0*64 + lane];
            float aL0 = attL[(size_t)s0*2 + h];
            float lg0 = hi*hj0;
            #pragma unroll
            for (int mm = 16; mm >= 1; mm >>= 1) lg0 += __shfl_xor(lg0, mm);
            float a0 = (aL0 + ai) / (1.0f + __expf(-lg0));
            a0 = (a0 > 0.0f) ? a0 : GNEG*a0;
            float mn = fmaxf(m, a0);
            float sc = __expf(m - mn);
            float w0 = __expf(a0 - mn);
            den = den*sc + w0;
            acc = acc*sc + w0*hj0;
            m = mn;
        }
        float accn = acc / (den + 1e-16f);
        float s_ = 0.5f*(accn + __shfl_xor(accn, 32)) + gb[c];
        yv = (s_ > 0.0f) ? 2.0f*s_ : (1.0f + NEGS)*s_;   // leaky(s)+s
        if (h == 0) y[(size_t)node*CCH + c] = yv;
    }
    if (h == 0){
        ssum[wv_*32 + c] = (node < NN) ? yv : 0.0f;
        ssq[wv_*32 + c]  = (node < NN) ? yv*yv : 0.0f;
    }
    __syncthreads();
    if (threadIdx.x < 32){
        float s = 0.0f, q = 0.0f;
        #pragma unroll
        for (int r = 0; r < 8; r++){
            s += ssum[r*32 + threadIdx.x];
            q += ssq[r*32 + threadIdx.x];
        }
        atomicAdd(&sums[threadIdx.x], s);
        atomicAdd(&sums[32 + threadIdx.x], q);
    }
}

// ============ BN normalize + accumulate (0 store, 1 add, 2 add+final leaky) ============
__global__ void k_norm(const float* __restrict__ y, const float* __restrict__ sums,
                       const float* __restrict__ gm, const float* __restrict__ bt,
                       float* __restrict__ acc, int mode){
    int t = blockIdx.x*blockDim.x + threadIdx.x;
    if (t >= NC) return;
    int c = t & 31;
    const float invN = 1.0f / (float)NN;
    float mu = sums[c] * invN;
    float var = sums[32 + c] * invN - mu*mu;
    float inv = 1.0f / sqrtf(var + BEPS);
    float v = gm[c] * (y[t] - mu) * inv + bt[c];
    if (mode == 0){
        acc[t] = v;
    } else if (mode == 1){
        acc[t] += v;
    } else {
        float a = acc[t] + v;
        acc[t] = (a > 0.0f) ? a : NEGS*a;
    }
}

extern "C" void kernel_launch(void* const* d_in, const int* in_sizes, int n_in,
                              void* d_out, int out_size, void* d_ws, size_t ws_size,
                              hipStream_t stream){
    const float* x   = (const float*)d_in[0];
    const int*   ei  = (const int*)d_in[1];
    const int*   src = ei;
    const int*   dst = ei + EE;

    const float *Wp[4], *cbp[4], *Gp[4], *alp[4], *arp[4], *gbp[4], *gmp[4], *btp[4];
    for (int b = 0; b < 4; b++){
        int base = 3 + 8*b;
        Wp[b]  = (const float*)d_in[base+0];
        cbp[b] = (const float*)d_in[base+1];
        Gp[b]  = (const float*)d_in[base+2];
        alp[b] = (const float*)d_in[base+3];
        arp[b] = (const float*)d_in[base+4];
        gbp[b] = (const float*)d_in[base+5];
        gmp[b] = (const float*)d_in[base+6];
        btp[b] = (const float*)d_in[base+7];
    }

    // 16B-aligned workspace carve-up
    char* w8 = (char*)d_ws;
    #define CARVE(ptr_t, name, bytes) ptr_t name = (ptr_t)w8; w8 += (((size_t)(bytes)) + 15) & ~(size_t)15;
    CARVE(float*, deg_out, sizeof(float)*NN)
    CARVE(int*,   indeg,   sizeof(int)*NN)
    CARVE(int*,   cur,     sizeof(int)*NN)
    CARVE(int*,   row,     sizeof(int)*(NN+1))
    CARVE(int*,   csr_src, sizeof(int)*ET)
    CARVE(float*, csr_w,   sizeof(float)*ET)
    CARVE(float*, T1,      sizeof(float)*NC)
    CARVE(float*, T2,      sizeof(float)*NC)
    CARVE(float*, T3,      sizeof(float)*NC)
    CARVE(float*, T4,      sizeof(float)*NC)
    CARVE(float*, Hh,      sizeof(float)*2*NC)
    CARVE(float*, attL,    sizeof(float)*2*NN)
    CARVE(float*, attR,    sizeof(float)*2*NN)
    CARVE(float*, yb,      sizeof(float)*NC)
    CARVE(float*, Wg,      sizeof(float)*4*5*2048)
    CARVE(float*, cbg,     sizeof(float)*4*64)
    CARVE(float*, sums,    sizeof(float)*64)

    float* acc = (float*)d_out;

    const int B = 256;
    const int gE  = (EE + B - 1)/B;
    const int gN  = (NN + B - 1)/B;
    const int gNC = (NC + B - 1)/B;
    const int gW5 = (NN*64 + 511)/512;      // one-wave-per-node @512

    // ---- CSR build ----
    hipMemsetAsync(deg_out, 0, (size_t)3*NN*sizeof(int), stream);  // deg_out, indeg, cur
    k_degs<<<gE, B, 0, stream>>>(src, dst, deg_out, indeg);
    k_scan<<<1, SCAN_T, 0, stream>>>(indeg, row);
    k_self<<<gN, B, 0, stream>>>(row, csr_src, csr_w);
    k_scatter<<<gE, B, 0, stream>>>(src, dst, deg_out, row, cur, csr_src, csr_w);

    // ---- shared Chebyshev basis ----
    k_spmv_csr<<<gW5, 512, 0, stream>>>(row, csr_src, csr_w, x,  (const float*)0, T1, 1);
    k_spmv_csr<<<gW5, 512, 0, stream>>>(row, csr_src, csr_w, T1, x,  T2, 0);
    k_spmv_csr<<<gW5, 512, 0, stream>>>(row, csr_src, csr_w, T2, T1, T3, 0);
    k_spmv_csr<<<gW5, 512, 0, stream>>>(row, csr_src, csr_w, T3, T2, T4, 0);

    // ---- per-block folded weights ----
    const int Ks[4] = {3, 3, 5, 5};
    for (int b = 0; b < 4; b++){
        int tot = Ks[b]*2048 + 64;
        k_wg<<<(tot + B - 1)/B, B, 0, stream>>>(Wp[b], cbp[b], Gp[b],
                                                Wg + b*5*2048, cbg + b*64, Ks[b]);
    }

    // ---- per-block pipeline ----
    for (int b = 0; b < 4; b++){
        k_hfused<<<gW5, 512, 0, stream>>>(x, T1, T2, T3, T4, Wg + b*5*2048, cbg + b*64,
                                          alp[b], arp[b], Ks[b], Hh, attL, attR);
        hipMemsetAsync(sums, 0, 64*sizeof(float), stream);
        k_gat<<<gW5, 512, 0, stream>>>(row, csr_src, Hh, attL, attR, gbp[b],
                                       yb, sums);
        int mode = (b == 0) ? 0 : ((b == 3) ? 2 : 1);
        k_norm<<<gNC, B, 0, stream>>>(yb, sums, gmp[b], btp[b], acc, mode);
    }
}

// Round 7
// 3285.517 us; speedup vs baseline: 1.5704x; 1.0040x over previous
//
#include <hip/hip_runtime.h>
#include <math.h>

#define NN 100000
#define EE 1600000
#define CCH 32
#define NC (NN*CCH)
#define ET (EE+NN)          // edges + self loops (one per node)
#define NEGS 0.01f
#define GNEG 0.2f
#define BEPS 1e-5f

// ============ CSR build ============

__global__ void k_degs(const int* __restrict__ src, const int* __restrict__ dst,
                       float* __restrict__ deg_out, int* __restrict__ indeg){
    int e = blockIdx.x*blockDim.x + threadIdx.x;
    if (e >= EE) return;
    atomicAdd(&deg_out[src[e]], 1.0f);
    atomicAdd(&indeg[dst[e]], 1);
}

#define SCAN_T 1024
__global__ void k_scan(const int* __restrict__ indeg, int* __restrict__ row){
    __shared__ int sdata[SCAN_T];
    int t = threadIdx.x;
    const int per = (NN + SCAN_T - 1)/SCAN_T;
    int lo = t*per, hi = (lo + per < NN) ? lo + per : NN;
    int s = 0;
    for (int d = lo; d < hi; d++) s += indeg[d] + 1;
    sdata[t] = s;
    __syncthreads();
    for (int off = 1; off < SCAN_T; off <<= 1){
        int v = (t >= off) ? sdata[t-off] : 0;
        __syncthreads();
        sdata[t] += v;
        __syncthreads();
    }
    int excl = (t == 0) ? 0 : sdata[t-1];
    for (int d = lo; d < hi; d++){
        row[d] = excl;
        excl += indeg[d] + 1;
    }
    if (t == 0) row[NN] = ET;
}

__global__ void k_self(const int* __restrict__ row, int* __restrict__ csr_src,
                       float* __restrict__ csr_w){
    int d = blockIdx.x*blockDim.x + threadIdx.x;
    if (d >= NN) return;
    int p = row[d];
    csr_src[p] = d;
    csr_w[p] = 0.0f;
}

__global__ void k_scatter(const int* __restrict__ src, const int* __restrict__ dst,
                          const float* __restrict__ deg_out, const int* __restrict__ row,
                          int* __restrict__ cur, int* __restrict__ csr_src,
                          float* __restrict__ csr_w){
    int e = blockIdx.x*blockDim.x + threadIdx.x;
    if (e >= EE) return;
    int s = src[e], d = dst[e];
    int pos = row[d] + 1 + atomicAdd(&cur[d], 1);
    csr_src[pos] = s;
    float di = deg_out[s] * deg_out[d];
    csr_w[pos] = (di > 0.0f) ? (-1.0f / sqrtf(fmaxf(di, 1e-12f))) : 0.0f;
}

// ============ gather SpMV: float2 channels, 4 edge-slots/wave, unroll x2 ============
__global__ void k_spmv_csr(const int* __restrict__ row, const int* __restrict__ csr_src,
                           const float* __restrict__ csr_w, const float* __restrict__ v,
                           const float* __restrict__ tprev, float* __restrict__ out, int first){
    int gid = blockIdx.x*blockDim.x + threadIdx.x;
    int node = gid >> 6;
    if (node >= NN) return;
    int lane = gid & 63;
    int slot = lane >> 4;       // 0..3
    int l = lane & 15;          // channel pair index
    const float2* V2 = (const float2*)v;
    int start = row[node] + 1, end = row[node+1];   // skip self-loop slot
    float2 acc = {0.0f, 0.0f};
    int p = start + slot;
    for (; p + 4 < end; p += 8){
        int s0 = csr_src[p], s1 = csr_src[p+4];
        float w0 = csr_w[p], w1 = csr_w[p+4];
        float2 v0 = V2[(size_t)s0*16 + l];
        float2 v1 = V2[(size_t)s1*16 + l];
        acc.x += w0*v0.x + w1*v1.x;
        acc.y += w0*v0.y + w1*v1.y;
    }
    if (p < end){
        float w0 = csr_w[p];
        float2 v0 = V2[(size_t)csr_src[p]*16 + l];
        acc.x += w0*v0.x;
        acc.y += w0*v0.y;
    }
    acc.x += __shfl_xor(acc.x, 32); acc.y += __shfl_xor(acc.y, 32);
    acc.x += __shfl_xor(acc.x, 16); acc.y += __shfl_xor(acc.y, 16);
    if (slot == 0){
        float2 r;
        if (first){
            r = acc;
        } else {
            float2 t = ((const float2*)tprev)[(size_t)node*16 + l];
            r.x = 2.0f*acc.x - t.x;
            r.y = 2.0f*acc.y - t.y;
        }
        ((float2*)out)[(size_t)node*16 + l] = r;
    }
}

// ============ Wg_k = W_k @ G, cbg = cb @ G (tiny) ============
__global__ void k_wg(const float* __restrict__ W, const float* __restrict__ cb,
                     const float* __restrict__ G, float* __restrict__ Wg,
                     float* __restrict__ cbg, int K){
    int t = blockIdx.x*blockDim.x + threadIdx.x;
    if (t < K*2048){
        int k = t >> 11, r = t & 2047;
        int i = r >> 6, j = r & 63;
        float s = 0.0f;
        #pragma unroll 8
        for (int q = 0; q < 32; q++) s += W[k*1024 + i*32 + q] * G[q*64 + j];
        Wg[t] = s;
    } else if (t < K*2048 + 64){
        int j = t - K*2048;
        float s = 0.0f;
        #pragma unroll 8
        for (int q = 0; q < 32; q++) s += cb[q] * G[q*64 + j];
        cbg[j] = s;
    }
}

// ============ H = (sum_k T_k @ Wg_k) + cbg; also attL/attR dots ============
__global__ void k_hfused(const float* __restrict__ T0, const float* __restrict__ T1,
                         const float* __restrict__ T2, const float* __restrict__ T3,
                         const float* __restrict__ T4,
                         const float* __restrict__ Wg, const float* __restrict__ cbg,
                         const float* __restrict__ al, const float* __restrict__ ar,
                         int K, float* __restrict__ Hh,
                         float* __restrict__ attL, float* __restrict__ attR){
    __shared__ float sW[5*2048];
    for (int i = threadIdx.x; i < K*2048; i += blockDim.x) sW[i] = Wg[i];
    __syncthreads();
    int gid = blockIdx.x*blockDim.x + threadIdx.x;
    int node = gid >> 6;
    if (node >= NN) return;
    int lane = gid & 63;
    int h = lane >> 5, c = lane & 31;
    const float* Ts[5] = {T0, T1, T2, T3, T4};
    float acc = cbg[lane];
    for (int k = 0; k < K; k++){
        float tv = Ts[k][(size_t)node*CCH + c];
        const float* wrow = &sW[k*2048];
        #pragma unroll
        for (int i = 0; i < 32; i++){
            float t = __shfl(tv, i);
            acc += t * wrow[i*64 + lane];
        }
    }
    Hh[(size_t)node*64 + lane] = acc;
    float va = acc * al[lane];
    float vr = acc * ar[lane];
    #pragma unroll
    for (int m = 16; m >= 1; m >>= 1){
        va += __shfl_xor(va, m);
        vr += __shfl_xor(vr, m);
    }
    if (c == 0){
        attL[(size_t)node*2 + h] = va;
        attR[(size_t)node*2 + h] = vr;
    }
}

// ============ fused SuperGAT, online softmax, unroll x4, SW-pipeline depth 2 ============
// one wave per dst node: 64 lanes = 2 heads x 32 channels
__global__ __launch_bounds__(512, 8)
void k_gat(const int* __restrict__ row, const int* __restrict__ csr_src,
           const float* __restrict__ Hh,
           const float* __restrict__ attL, const float* __restrict__ attR,
           const float* __restrict__ gb,
           float* __restrict__ y, float* __restrict__ sums){
    int gid = blockIdx.x*blockDim.x + threadIdx.x;
    int node = gid >> 6;
    int lane = gid & 63;
    int wv_ = threadIdx.x >> 6;
    int h = lane >> 5, c = lane & 31;
    __shared__ float ssum[8*32], ssq[8*32];
    float yv = 0.0f;
    if (node < NN){
        float hi = Hh[(size_t)node*64 + lane];
        float ai = attR[(size_t)node*2 + h];
        int start = row[node], end = row[node+1];
        int cnt = end - start;
        int ng = cnt >> 2;
        int endg = start + (ng << 2);
        float m = -1e30f, den = 0.0f, acc = 0.0f;

        int   sA0,sA1,sA2,sA3, sB0,sB1,sB2,sB3;
        float hA0,hA1,hA2,hA3, aA0,aA1,aA2,aA3;
        float hB0,hB1,hB2,hB3, aB0,aB1,aB2,aB3;

        #define GLOAD(P,S0,S1,S2,S3,H0,H1,H2,H3,A0,A1,A2,A3) do{                 \
            S0=csr_src[(P)]; S1=csr_src[(P)+1]; S2=csr_src[(P)+2]; S3=csr_src[(P)+3]; \
            H0=Hh[(size_t)S0*64+lane]; H1=Hh[(size_t)S1*64+lane];                \
            H2=Hh[(size_t)S2*64+lane]; H3=Hh[(size_t)S3*64+lane];                \
            A0=attL[(size_t)S0*2+h];   A1=attL[(size_t)S1*2+h];                  \
            A2=attL[(size_t)S2*2+h];   A3=attL[(size_t)S3*2+h]; }while(0)

        #define PROC(H0,H1,H2,H3,A0,A1,A2,A3) do{                                \
            float lg0=hi*H0, lg1=hi*H1, lg2=hi*H2, lg3=hi*H3;                    \
            _Pragma("unroll")                                                    \
            for (int mm=16; mm>=1; mm>>=1){                                      \
                lg0 += __shfl_xor(lg0,mm); lg1 += __shfl_xor(lg1,mm);            \
                lg2 += __shfl_xor(lg2,mm); lg3 += __shfl_xor(lg3,mm); }          \
            float a0=(A0+ai)/(1.0f+__expf(-lg0));                                \
            float a1=(A1+ai)/(1.0f+__expf(-lg1));                                \
            float a2=(A2+ai)/(1.0f+__expf(-lg2));                                \
            float a3=(A3+ai)/(1.0f+__expf(-lg3));                                \
            a0=(a0>0.0f)?a0:GNEG*a0; a1=(a1>0.0f)?a1:GNEG*a1;                    \
            a2=(a2>0.0f)?a2:GNEG*a2; a3=(a3>0.0f)?a3:GNEG*a3;                    \
            float mn=fmaxf(fmaxf(m,fmaxf(a0,a1)),fmaxf(a2,a3));                  \
            float sc=__expf(m-mn);                                               \
            float w0=__expf(a0-mn), w1=__expf(a1-mn);                            \
            float w2=__expf(a2-mn), w3=__expf(a3-mn);                            \
            den=den*sc+((w0+w1)+(w2+w3));                                        \
            acc=acc*sc+(w0*H0+w1*H1)+(w2*H2+w3*H3);                              \
            m=mn; }while(0)

        if (ng >= 2){
            GLOAD(start,   sA0,sA1,sA2,sA3, hA0,hA1,hA2,hA3, aA0,aA1,aA2,aA3);
            GLOAD(start+4, sB0,sB1,sB2,sB3, hB0,hB1,hB2,hB3, aB0,aB1,aB2,aB3);
            int lp = start + 8;
            int gp = start;
            while (1){
                PROC(hA0,hA1,hA2,hA3, aA0,aA1,aA2,aA3);
                gp += 4;
                if (gp >= endg) break;
                if (lp < endg){
                    GLOAD(lp, sA0,sA1,sA2,sA3, hA0,hA1,hA2,hA3, aA0,aA1,aA2,aA3);
                    lp += 4;
                }
                PROC(hB0,hB1,hB2,hB3, aB0,aB1,aB2,aB3);
                gp += 4;
                if (gp >= endg) break;
                if (lp < endg){
                    GLOAD(lp, sB0,sB1,sB2,sB3, hB0,hB1,hB2,hB3, aB0,aB1,aB2,aB3);
                    lp += 4;
                }
            }
        } else if (ng == 1){
            GLOAD(start, sA0,sA1,sA2,sA3, hA0,hA1,hA2,hA3, aA0,aA1,aA2,aA3);
            PROC(hA0,hA1,hA2,hA3, aA0,aA1,aA2,aA3);
        }
        // tail (0..3 edges)
        for (int p = endg; p < end; p++){
            int s0 = csr_src[p];
            float hj0 = Hh[(size_t)s0*64 + lane];
            float aL0 = attL[(size_t)s0*2 + h];
            float lg0 = hi*hj0;
            #pragma unroll
            for (int mm = 16; mm >= 1; mm >>= 1) lg0 += __shfl_xor(lg0, mm);
            float a0 = (aL0 + ai) / (1.0f + __expf(-lg0));
            a0 = (a0 > 0.0f) ? a0 : GNEG*a0;
            float mn = fmaxf(m, a0);
            float sc = __expf(m - mn);
            float w0 = __expf(a0 - mn);
            den = den*sc + w0;
            acc = acc*sc + w0*hj0;
            m = mn;
        }
        float accn = acc / (den + 1e-16f);
        float s_ = 0.5f*(accn + __shfl_xor(accn, 32)) + gb[c];
        yv = (s_ > 0.0f) ? 2.0f*s_ : (1.0f + NEGS)*s_;   // leaky(s)+s
        if (h == 0) y[(size_t)node*CCH + c] = yv;
    }
    if (h == 0){
        ssum[wv_*32 + c] = (node < NN) ? yv : 0.0f;
        ssq[wv_*32 + c]  = (node < NN) ? yv*yv : 0.0f;
    }
    __syncthreads();
    if (threadIdx.x < 32){
        float s = 0.0f, q = 0.0f;
        #pragma unroll
        for (int r = 0; r < 8; r++){
            s += ssum[r*32 + threadIdx.x];
            q += ssq[r*32 + threadIdx.x];
        }
        atomicAdd(&sums[threadIdx.x], s);
        atomicAdd(&sums[32 + threadIdx.x], q);
    }
}

// ============ BN normalize + accumulate (0 store, 1 add, 2 add+final leaky) ============
__global__ void k_norm(const float* __restrict__ y, const float* __restrict__ sums,
                       const float* __restrict__ gm, const float* __restrict__ bt,
                       float* __restrict__ acc, int mode){
    int t = blockIdx.x*blockDim.x + threadIdx.x;
    if (t >= NC) return;
    int c = t & 31;
    const float invN = 1.0f / (float)NN;
    float mu = sums[c] * invN;
    float var = sums[32 + c] * invN - mu*mu;
    float inv = 1.0f / sqrtf(var + BEPS);
    float v = gm[c] * (y[t] - mu) * inv + bt[c];
    if (mode == 0){
        acc[t] = v;
    } else if (mode == 1){
        acc[t] += v;
    } else {
        float a = acc[t] + v;
        acc[t] = (a > 0.0f) ? a : NEGS*a;
    }
}

extern "C" void kernel_launch(void* const* d_in, const int* in_sizes, int n_in,
                              void* d_out, int out_size, void* d_ws, size_t ws_size,
                              hipStream_t stream){
    const float* x   = (const float*)d_in[0];
    const int*   ei  = (const int*)d_in[1];
    const int*   src = ei;
    const int*   dst = ei + EE;

    const float *Wp[4], *cbp[4], *Gp[4], *alp[4], *arp[4], *gbp[4], *gmp[4], *btp[4];
    for (int b = 0; b < 4; b++){
        int base = 3 + 8*b;
        Wp[b]  = (const float*)d_in[base+0];
        cbp[b] = (const float*)d_in[base+1];
        Gp[b]  = (const float*)d_in[base+2];
        alp[b] = (const float*)d_in[base+3];
        arp[b] = (const float*)d_in[base+4];
        gbp[b] = (const float*)d_in[base+5];
        gmp[b] = (const float*)d_in[base+6];
        btp[b] = (const float*)d_in[base+7];
    }

    // 16B-aligned workspace carve-up
    char* w8 = (char*)d_ws;
    #define CARVE(ptr_t, name, bytes) ptr_t name = (ptr_t)w8; w8 += (((size_t)(bytes)) + 15) & ~(size_t)15;
    CARVE(float*, deg_out, sizeof(float)*NN)
    CARVE(int*,   indeg,   sizeof(int)*NN)
    CARVE(int*,   cur,     sizeof(int)*NN)
    CARVE(int*,   row,     sizeof(int)*(NN+1))
    CARVE(int*,   csr_src, sizeof(int)*ET)
    CARVE(float*, csr_w,   sizeof(float)*ET)
    CARVE(float*, T1,      sizeof(float)*NC)
    CARVE(float*, T2,      sizeof(float)*NC)
    CARVE(float*, T3,      sizeof(float)*NC)
    CARVE(float*, T4,      sizeof(float)*NC)
    CARVE(float*, Hh,      sizeof(float)*2*NC)
    CARVE(float*, attL,    sizeof(float)*2*NN)
    CARVE(float*, attR,    sizeof(float)*2*NN)
    CARVE(float*, yb,      sizeof(float)*NC)
    CARVE(float*, Wg,      sizeof(float)*4*5*2048)
    CARVE(float*, cbg,     sizeof(float)*4*64)
    CARVE(float*, sums,    sizeof(float)*64)

    float* acc = (float*)d_out;

    const int B = 256;
    const int gE  = (EE + B - 1)/B;
    const int gN  = (NN + B - 1)/B;
    const int gNC = (NC + B - 1)/B;
    const int gW5 = (NN*64 + 511)/512;      // one-wave-per-node @512

    // ---- CSR build ----
    hipMemsetAsync(deg_out, 0, (size_t)3*NN*sizeof(int), stream);  // deg_out, indeg, cur
    k_degs<<<gE, B, 0, stream>>>(src, dst, deg_out, indeg);
    k_scan<<<1, SCAN_T, 0, stream>>>(indeg, row);
    k_self<<<gN, B, 0, stream>>>(row, csr_src, csr_w);
    k_scatter<<<gE, B, 0, stream>>>(src, dst, deg_out, row, cur, csr_src, csr_w);

    // ---- shared Chebyshev basis ----
    k_spmv_csr<<<gW5, 512, 0, stream>>>(row, csr_src, csr_w, x,  (const float*)0, T1, 1);
    k_spmv_csr<<<gW5, 512, 0, stream>>>(row, csr_src, csr_w, T1, x,  T2, 0);
    k_spmv_csr<<<gW5, 512, 0, stream>>>(row, csr_src, csr_w, T2, T1, T3, 0);
    k_spmv_csr<<<gW5, 512, 0, stream>>>(row, csr_src, csr_w, T3, T2, T4, 0);

    // ---- per-block folded weights ----
    const int Ks[4] = {3, 3, 5, 5};
    for (int b = 0; b < 4; b++){
        int tot = Ks[b]*2048 + 64;
        k_wg<<<(tot + B - 1)/B, B, 0, stream>>>(Wp[b], cbp[b], Gp[b],
                                                Wg + b*5*2048, cbg + b*64, Ks[b]);
    }

    // ---- per-block pipeline ----
    for (int b = 0; b < 4; b++){
        k_hfused<<<gW5, 512, 0, stream>>>(x, T1, T2, T3, T4, Wg + b*5*2048, cbg + b*64,
                                          alp[b], arp[b], Ks[b], Hh, attL, attR);
        hipMemsetAsync(sums, 0, 64*sizeof(float), stream);
        k_gat<<<gW5, 512, 0, stream>>>(row, csr_src, Hh, attL, attR, gbp[b],
                                       yb, sums);
        int mode = (b == 0) ? 0 : ((b == 3) ? 2 : 1);
        k_norm<<<gNC, B, 0, stream>>>(yb, sums, gmp[b], btp[b], acc, mode);
    }
}

// Round 8
// 2333.618 us; speedup vs baseline: 2.2110x; 1.4079x over previous
//
#include <hip/hip_runtime.h>
#include <math.h>

#define NN 100000
#define EE 1600000
#define CCH 32
#define NC (NN*CCH)
#define ET (EE+NN)          // edges + self loops (one per node)
#define NEGS 0.01f
#define GNEG 0.2f
#define BEPS 1e-5f

// ============ CSR build ============

__global__ void k_degs(const int* __restrict__ src, const int* __restrict__ dst,
                       float* __restrict__ deg_out, int* __restrict__ indeg){
    int e = blockIdx.x*blockDim.x + threadIdx.x;
    if (e >= EE) return;
    atomicAdd(&deg_out[src[e]], 1.0f);
    atomicAdd(&indeg[dst[e]], 1);
}

#define SCAN_T 1024
__global__ void k_scan(const int* __restrict__ indeg, int* __restrict__ row){
    __shared__ int sdata[SCAN_T];
    int t = threadIdx.x;
    const int per = (NN + SCAN_T - 1)/SCAN_T;
    int lo = t*per, hi = (lo + per < NN) ? lo + per : NN;
    int s = 0;
    for (int d = lo; d < hi; d++) s += indeg[d] + 1;
    sdata[t] = s;
    __syncthreads();
    for (int off = 1; off < SCAN_T; off <<= 1){
        int v = (t >= off) ? sdata[t-off] : 0;
        __syncthreads();
        sdata[t] += v;
        __syncthreads();
    }
    int excl = (t == 0) ? 0 : sdata[t-1];
    for (int d = lo; d < hi; d++){
        row[d] = excl;
        excl += indeg[d] + 1;
    }
    if (t == 0) row[NN] = ET;
}

__global__ void k_self(const int* __restrict__ row, int* __restrict__ csr_src,
                       float* __restrict__ csr_w){
    int d = blockIdx.x*blockDim.x + threadIdx.x;
    if (d >= NN) return;
    int p = row[d];
    csr_src[p] = d;
    csr_w[p] = 0.0f;
}

__global__ void k_scatter(const int* __restrict__ src, const int* __restrict__ dst,
                          const float* __restrict__ deg_out, const int* __restrict__ row,
                          int* __restrict__ cur, int* __restrict__ csr_src,
                          float* __restrict__ csr_w){
    int e = blockIdx.x*blockDim.x + threadIdx.x;
    if (e >= EE) return;
    int s = src[e], d = dst[e];
    int pos = row[d] + 1 + atomicAdd(&cur[d], 1);
    csr_src[pos] = s;
    float di = deg_out[s] * deg_out[d];
    csr_w[pos] = (di > 0.0f) ? (-1.0f / sqrtf(fmaxf(di, 1e-12f))) : 0.0f;
}

// ============ gather SpMV: float2 channels, 4 edge-slots/wave, unroll x2 ============
__global__ void k_spmv_csr(const int* __restrict__ row, const int* __restrict__ csr_src,
                           const float* __restrict__ csr_w, const float* __restrict__ v,
                           const float* __restrict__ tprev, float* __restrict__ out, int first){
    int gid = blockIdx.x*blockDim.x + threadIdx.x;
    int node = gid >> 6;
    if (node >= NN) return;
    int lane = gid & 63;
    int slot = lane >> 4;       // 0..3
    int l = lane & 15;          // channel pair index
    const float2* V2 = (const float2*)v;
    int start = row[node] + 1, end = row[node+1];   // skip self-loop slot
    float2 acc = {0.0f, 0.0f};
    int p = start + slot;
    for (; p + 4 < end; p += 8){
        int s0 = csr_src[p], s1 = csr_src[p+4];
        float w0 = csr_w[p], w1 = csr_w[p+4];
        float2 v0 = V2[(size_t)s0*16 + l];
        float2 v1 = V2[(size_t)s1*16 + l];
        acc.x += w0*v0.x + w1*v1.x;
        acc.y += w0*v0.y + w1*v1.y;
    }
    if (p < end){
        float w0 = csr_w[p];
        float2 v0 = V2[(size_t)csr_src[p]*16 + l];
        acc.x += w0*v0.x;
        acc.y += w0*v0.y;
    }
    acc.x += __shfl_xor(acc.x, 32); acc.y += __shfl_xor(acc.y, 32);
    acc.x += __shfl_xor(acc.x, 16); acc.y += __shfl_xor(acc.y, 16);
    if (slot == 0){
        float2 r;
        if (first){
            r = acc;
        } else {
            float2 t = ((const float2*)tprev)[(size_t)node*16 + l];
            r.x = 2.0f*acc.x - t.x;
            r.y = 2.0f*acc.y - t.y;
        }
        ((float2*)out)[(size_t)node*16 + l] = r;
    }
}

// ============ Wg_k = W_k @ G, cbg = cb @ G (tiny) ============
__global__ void k_wg(const float* __restrict__ W, const float* __restrict__ cb,
                     const float* __restrict__ G, float* __restrict__ Wg,
                     float* __restrict__ cbg, int K){
    int t = blockIdx.x*blockDim.x + threadIdx.x;
    if (t < K*2048){
        int k = t >> 11, r = t & 2047;
        int i = r >> 6, j = r & 63;
        float s = 0.0f;
        #pragma unroll 8
        for (int q = 0; q < 32; q++) s += W[k*1024 + i*32 + q] * G[q*64 + j];
        Wg[t] = s;
    } else if (t < K*2048 + 64){
        int j = t - K*2048;
        float s = 0.0f;
        #pragma unroll 8
        for (int q = 0; q < 32; q++) s += cb[q] * G[q*64 + j];
        cbg[j] = s;
    }
}

// ============ H_b = (sum_k T_k @ Wg_k) + cbg; writes interleaved H4 + att dots ============
// H4 layout: [node][lane(64)][block(4)]; attL4/attR4: [node][head(2)][block(4)]
__global__ void k_hfused(const float* __restrict__ T0, const float* __restrict__ T1,
                         const float* __restrict__ T2, const float* __restrict__ T3,
                         const float* __restrict__ T4,
                         const float* __restrict__ Wg, const float* __restrict__ cbg,
                         const float* __restrict__ al, const float* __restrict__ ar,
                         int K, int b, float* __restrict__ H4,
                         float* __restrict__ attL4, float* __restrict__ attR4){
    __shared__ float sW[5*2048];
    for (int i = threadIdx.x; i < K*2048; i += blockDim.x) sW[i] = Wg[i];
    __syncthreads();
    int gid = blockIdx.x*blockDim.x + threadIdx.x;
    int node = gid >> 6;
    if (node >= NN) return;
    int lane = gid & 63;
    int h = lane >> 5, c = lane & 31;
    const float* Ts[5] = {T0, T1, T2, T3, T4};
    float acc = cbg[lane];
    for (int k = 0; k < K; k++){
        float tv = Ts[k][(size_t)node*CCH + c];
        const float* wrow = &sW[k*2048];
        #pragma unroll
        for (int i = 0; i < 32; i++){
            float t = __shfl(tv, i);
            acc += t * wrow[i*64 + lane];
        }
    }
    H4[(size_t)node*256 + lane*4 + b] = acc;
    float va = acc * al[lane];
    float vr = acc * ar[lane];
    #pragma unroll
    for (int m = 16; m >= 1; m >>= 1){
        va += __shfl_xor(va, m);
        vr += __shfl_xor(vr, m);
    }
    if (c == 0){
        attL4[(size_t)node*8 + h*4 + b] = va;
        attR4[(size_t)node*8 + h*4 + b] = vr;
    }
}

// ============ fused SuperGAT for ALL 4 blocks, online softmax, 4-edge groups ============
// one wave per dst node; lane = head(1b)|chan(5b); per lane float4 = 4 blocks
__global__ __launch_bounds__(512)
void k_gat4(const int* __restrict__ row, const int* __restrict__ csr_src,
            const float* __restrict__ H4,
            const float* __restrict__ attL4, const float* __restrict__ attR4,
            const float* __restrict__ gb0, const float* __restrict__ gb1,
            const float* __restrict__ gb2, const float* __restrict__ gb3,
            float* __restrict__ y4, float* __restrict__ sums){
    int gid = blockIdx.x*blockDim.x + threadIdx.x;
    int node = gid >> 6;
    int lane = gid & 63;
    int wv_ = threadIdx.x >> 6;
    int h = lane >> 5, c = lane & 31;
    __shared__ float4 ssum[8*32], ssq[8*32];
    float4 yv = {0.0f, 0.0f, 0.0f, 0.0f};
    if (node < NN){
        float hiA[4], aiA[4], mA[4], denA[4], accA[4];
        {
            float4 t = *(const float4*)&H4[(size_t)node*256 + lane*4];
            hiA[0]=t.x; hiA[1]=t.y; hiA[2]=t.z; hiA[3]=t.w;
            float4 u = *(const float4*)&attR4[(size_t)node*8 + h*4];
            aiA[0]=u.x; aiA[1]=u.y; aiA[2]=u.z; aiA[3]=u.w;
        }
        #pragma unroll
        for (int k = 0; k < 4; k++){ mA[k] = -1e30f; denA[k] = 0.0f; accA[k] = 0.0f; }
        int start = row[node], end = row[node+1];
        int p = start;
        for (; p + 3 < end; p += 4){
            int s[4]; float hj[4][4], aL[4][4], lg[4][4];
            #pragma unroll
            for (int i = 0; i < 4; i++) s[i] = csr_src[p+i];
            #pragma unroll
            for (int i = 0; i < 4; i++){
                float4 t = *(const float4*)&H4[(size_t)s[i]*256 + lane*4];
                hj[i][0]=t.x; hj[i][1]=t.y; hj[i][2]=t.z; hj[i][3]=t.w;
                float4 u = *(const float4*)&attL4[(size_t)s[i]*8 + h*4];
                aL[i][0]=u.x; aL[i][1]=u.y; aL[i][2]=u.z; aL[i][3]=u.w;
            }
            #pragma unroll
            for (int i = 0; i < 4; i++)
                #pragma unroll
                for (int k = 0; k < 4; k++) lg[i][k] = hiA[k]*hj[i][k];
            #pragma unroll
            for (int mm = 16; mm >= 1; mm >>= 1)
                #pragma unroll
                for (int i = 0; i < 4; i++)
                    #pragma unroll
                    for (int k = 0; k < 4; k++) lg[i][k] += __shfl_xor(lg[i][k], mm);
            #pragma unroll
            for (int k = 0; k < 4; k++){
                float a0 = (aL[0][k] + aiA[k]) / (1.0f + __expf(-lg[0][k]));
                float a1 = (aL[1][k] + aiA[k]) / (1.0f + __expf(-lg[1][k]));
                float a2 = (aL[2][k] + aiA[k]) / (1.0f + __expf(-lg[2][k]));
                float a3 = (aL[3][k] + aiA[k]) / (1.0f + __expf(-lg[3][k]));
                a0 = (a0 > 0.0f) ? a0 : GNEG*a0;
                a1 = (a1 > 0.0f) ? a1 : GNEG*a1;
                a2 = (a2 > 0.0f) ? a2 : GNEG*a2;
                a3 = (a3 > 0.0f) ? a3 : GNEG*a3;
                float mn = fmaxf(fmaxf(mA[k], fmaxf(a0, a1)), fmaxf(a2, a3));
                float sc = __expf(mA[k] - mn);
                float w0 = __expf(a0 - mn), w1 = __expf(a1 - mn);
                float w2 = __expf(a2 - mn), w3 = __expf(a3 - mn);
                denA[k] = denA[k]*sc + ((w0 + w1) + (w2 + w3));
                accA[k] = accA[k]*sc + (w0*hj[0][k] + w1*hj[1][k]) + (w2*hj[2][k] + w3*hj[3][k]);
                mA[k] = mn;
            }
        }
        for (; p < end; p++){
            int s0 = csr_src[p];
            float hj0[4], aL0[4], lg0[4];
            float4 t = *(const float4*)&H4[(size_t)s0*256 + lane*4];
            hj0[0]=t.x; hj0[1]=t.y; hj0[2]=t.z; hj0[3]=t.w;
            float4 u = *(const float4*)&attL4[(size_t)s0*8 + h*4];
            aL0[0]=u.x; aL0[1]=u.y; aL0[2]=u.z; aL0[3]=u.w;
            #pragma unroll
            for (int k = 0; k < 4; k++) lg0[k] = hiA[k]*hj0[k];
            #pragma unroll
            for (int mm = 16; mm >= 1; mm >>= 1)
                #pragma unroll
                for (int k = 0; k < 4; k++) lg0[k] += __shfl_xor(lg0[k], mm);
            #pragma unroll
            for (int k = 0; k < 4; k++){
                float a0 = (aL0[k] + aiA[k]) / (1.0f + __expf(-lg0[k]));
                a0 = (a0 > 0.0f) ? a0 : GNEG*a0;
                float mn = fmaxf(mA[k], a0);
                float sc = __expf(mA[k] - mn);
                float w0 = __expf(a0 - mn);
                denA[k] = denA[k]*sc + w0;
                accA[k] = accA[k]*sc + w0*hj0[k];
                mA[k] = mn;
            }
        }
        float g[4];
        g[0] = gb0[c]; g[1] = gb1[c]; g[2] = gb2[c]; g[3] = gb3[c];
        float yo[4];
        #pragma unroll
        for (int k = 0; k < 4; k++){
            float accn = accA[k] / (denA[k] + 1e-16f);
            float s_ = 0.5f*(accn + __shfl_xor(accn, 32)) + g[k];
            yo[k] = (s_ > 0.0f) ? 2.0f*s_ : (1.0f + NEGS)*s_;   // leaky(s)+s
        }
        yv.x = yo[0]; yv.y = yo[1]; yv.z = yo[2]; yv.w = yo[3];
        if (h == 0) *(float4*)&y4[(size_t)node*128 + c*4] = yv;
    }
    if (h == 0){
        ssum[wv_*32 + c] = yv;
        float4 q = {yv.x*yv.x, yv.y*yv.y, yv.z*yv.z, yv.w*yv.w};
        ssq[wv_*32 + c] = q;
    }
    __syncthreads();
    if (threadIdx.x < 32){
        float4 s = {0,0,0,0}, q = {0,0,0,0};
        #pragma unroll
        for (int r = 0; r < 8; r++){
            float4 a = ssum[r*32 + threadIdx.x];
            float4 b = ssq[r*32 + threadIdx.x];
            s.x += a.x; s.y += a.y; s.z += a.z; s.w += a.w;
            q.x += b.x; q.y += b.y; q.z += b.z; q.w += b.w;
        }
        atomicAdd(&sums[  0 + threadIdx.x], s.x);
        atomicAdd(&sums[ 32 + threadIdx.x], s.y);
        atomicAdd(&sums[ 64 + threadIdx.x], s.z);
        atomicAdd(&sums[ 96 + threadIdx.x], s.w);
        atomicAdd(&sums[128 + threadIdx.x], q.x);
        atomicAdd(&sums[160 + threadIdx.x], q.y);
        atomicAdd(&sums[192 + threadIdx.x], q.z);
        atomicAdd(&sums[224 + threadIdx.x], q.w);
    }
}

// ============ BN normalize all 4 blocks + sum + final leaky, one pass ============
__global__ void k_norm4(const float* __restrict__ y4, const float* __restrict__ sums,
                        const float* __restrict__ gm0, const float* __restrict__ bt0,
                        const float* __restrict__ gm1, const float* __restrict__ bt1,
                        const float* __restrict__ gm2, const float* __restrict__ bt2,
                        const float* __restrict__ gm3, const float* __restrict__ bt3,
                        float* __restrict__ out){
    int t = blockIdx.x*blockDim.x + threadIdx.x;
    if (t >= NC) return;
    int c = t & 31;
    const float invN = 1.0f / (float)NN;
    float4 v = *(const float4*)&y4[(size_t)t*4];
    float r = 0.0f;
    {
        float mu = sums[c]*invN;       float var = sums[128+c]*invN - mu*mu;
        r += gm0[c]*(v.x - mu)/sqrtf(var + BEPS) + bt0[c];
    }
    {
        float mu = sums[32+c]*invN;    float var = sums[160+c]*invN - mu*mu;
        r += gm1[c]*(v.y - mu)/sqrtf(var + BEPS) + bt1[c];
    }
    {
        float mu = sums[64+c]*invN;    float var = sums[192+c]*invN - mu*mu;
        r += gm2[c]*(v.z - mu)/sqrtf(var + BEPS) + bt2[c];
    }
    {
        float mu = sums[96+c]*invN;    float var = sums[224+c]*invN - mu*mu;
        r += gm3[c]*(v.w - mu)/sqrtf(var + BEPS) + bt3[c];
    }
    out[t] = (r > 0.0f) ? r : NEGS*r;
}

extern "C" void kernel_launch(void* const* d_in, const int* in_sizes, int n_in,
                              void* d_out, int out_size, void* d_ws, size_t ws_size,
                              hipStream_t stream){
    const float* x   = (const float*)d_in[0];
    const int*   ei  = (const int*)d_in[1];
    const int*   src = ei;
    const int*   dst = ei + EE;

    const float *Wp[4], *cbp[4], *Gp[4], *alp[4], *arp[4], *gbp[4], *gmp[4], *btp[4];
    for (int b = 0; b < 4; b++){
        int base = 3 + 8*b;
        Wp[b]  = (const float*)d_in[base+0];
        cbp[b] = (const float*)d_in[base+1];
        Gp[b]  = (const float*)d_in[base+2];
        alp[b] = (const float*)d_in[base+3];
        arp[b] = (const float*)d_in[base+4];
        gbp[b] = (const float*)d_in[base+5];
        gmp[b] = (const float*)d_in[base+6];
        btp[b] = (const float*)d_in[base+7];
    }

    // 16B-aligned workspace carve-up
    char* w8 = (char*)d_ws;
    #define CARVE(ptr_t, name, bytes) ptr_t name = (ptr_t)w8; w8 += (((size_t)(bytes)) + 15) & ~(size_t)15;
    CARVE(float*, deg_out, sizeof(float)*NN)
    CARVE(int*,   indeg,   sizeof(int)*NN)
    CARVE(int*,   cur,     sizeof(int)*NN)
    CARVE(int*,   row,     sizeof(int)*(NN+1))
    CARVE(int*,   csr_src, sizeof(int)*ET)
    CARVE(float*, csr_w,   sizeof(float)*ET)
    CARVE(float*, T1,      sizeof(float)*NC)      // T1..T4 contiguous; y4 aliases them later
    CARVE(float*, T2,      sizeof(float)*NC)
    CARVE(float*, T3,      sizeof(float)*NC)
    CARVE(float*, T4,      sizeof(float)*NC)
    CARVE(float*, H4,      sizeof(float)*(size_t)NN*256)
    CARVE(float*, attL4,   sizeof(float)*NN*8)
    CARVE(float*, attR4,   sizeof(float)*NN*8)
    CARVE(float*, Wg,      sizeof(float)*4*5*2048)
    CARVE(float*, cbg,     sizeof(float)*4*64)
    CARVE(float*, sums,    sizeof(float)*256)
    float* y4 = T1;   // T1..T4 are dead after the last k_hfused; y4 = NN*128 floats = their exact span

    float* acc = (float*)d_out;

    const int B = 256;
    const int gE  = (EE + B - 1)/B;
    const int gN  = (NN + B - 1)/B;
    const int gNC = (NC + B - 1)/B;
    const int gW5 = (NN*64 + 511)/512;      // one-wave-per-node @512

    // ---- CSR build ----
    hipMemsetAsync(deg_out, 0, (size_t)3*NN*sizeof(int), stream);  // deg_out, indeg, cur
    k_degs<<<gE, B, 0, stream>>>(src, dst, deg_out, indeg);
    k_scan<<<1, SCAN_T, 0, stream>>>(indeg, row);
    k_self<<<gN, B, 0, stream>>>(row, csr_src, csr_w);
    k_scatter<<<gE, B, 0, stream>>>(src, dst, deg_out, row, cur, csr_src, csr_w);

    // ---- shared Chebyshev basis ----
    k_spmv_csr<<<gW5, 512, 0, stream>>>(row, csr_src, csr_w, x,  (const float*)0, T1, 1);
    k_spmv_csr<<<gW5, 512, 0, stream>>>(row, csr_src, csr_w, T1, x,  T2, 0);
    k_spmv_csr<<<gW5, 512, 0, stream>>>(row, csr_src, csr_w, T2, T1, T3, 0);
    k_spmv_csr<<<gW5, 512, 0, stream>>>(row, csr_src, csr_w, T3, T2, T4, 0);

    // ---- per-block folded weights ----
    const int Ks[4] = {3, 3, 5, 5};
    for (int b = 0; b < 4; b++){
        int tot = Ks[b]*2048 + 64;
        k_wg<<<(tot + B - 1)/B, B, 0, stream>>>(Wp[b], cbp[b], Gp[b],
                                                Wg + b*5*2048, cbg + b*64, Ks[b]);
    }

    // ---- H for all 4 blocks (interleaved layout) ----
    for (int b = 0; b < 4; b++){
        k_hfused<<<gW5, 512, 0, stream>>>(x, T1, T2, T3, T4, Wg + b*5*2048, cbg + b*64,
                                          alp[b], arp[b], Ks[b], b, H4, attL4, attR4);
    }

    // ---- fused SuperGAT over all 4 blocks (y4 overwrites T1..T4 space) ----
    hipMemsetAsync(sums, 0, 256*sizeof(float), stream);
    k_gat4<<<gW5, 512, 0, stream>>>(row, csr_src, H4, attL4, attR4,
                                    gbp[0], gbp[1], gbp[2], gbp[3], y4, sums);

    // ---- BN + sum + final leaky, single pass ----
    k_norm4<<<gNC, B, 0, stream>>>(y4, sums,
                                   gmp[0], btp[0], gmp[1], btp[1],
                                   gmp[2], btp[2], gmp[3], btp[3], acc);
}

// Round 9
// 2105.011 us; speedup vs baseline: 2.4511x; 1.1086x over previous
//
#include <hip/hip_runtime.h>
#include <math.h>

#define NN 100000
#define EE 1600000
#define CCH 32
#define NC (NN*CCH)
#define ET (EE+NN)          // edges + self loops (one per node)
#define NEGS 0.01f
#define GNEG 0.2f
#define BEPS 1e-5f

// ds_swizzle BitMode XOR patterns (within 32-lane groups), zero address setup
#define DSWZ(x, pat) __int_as_float(__builtin_amdgcn_ds_swizzle(__float_as_int(x), pat))
#define RED32(v) do{ v += DSWZ(v,0x041F); v += DSWZ(v,0x081F); v += DSWZ(v,0x101F); \
                     v += DSWZ(v,0x201F); v += DSWZ(v,0x401F); }while(0)

// ============ CSR build ============

__global__ void k_degs(const int* __restrict__ src, const int* __restrict__ dst,
                       float* __restrict__ deg_out, int* __restrict__ indeg){
    int e = blockIdx.x*blockDim.x + threadIdx.x;
    if (e >= EE) return;
    atomicAdd(&deg_out[src[e]], 1.0f);
    atomicAdd(&indeg[dst[e]], 1);
}

#define SCAN_T 1024
__global__ void k_scan(const int* __restrict__ indeg, int* __restrict__ row){
    __shared__ int sdata[SCAN_T];
    int t = threadIdx.x;
    const int per = (NN + SCAN_T - 1)/SCAN_T;
    int lo = t*per, hi = (lo + per < NN) ? lo + per : NN;
    int s = 0;
    for (int d = lo; d < hi; d++) s += indeg[d] + 1;
    sdata[t] = s;
    __syncthreads();
    for (int off = 1; off < SCAN_T; off <<= 1){
        int v = (t >= off) ? sdata[t-off] : 0;
        __syncthreads();
        sdata[t] += v;
        __syncthreads();
    }
    int excl = (t == 0) ? 0 : sdata[t-1];
    for (int d = lo; d < hi; d++){
        row[d] = excl;
        excl += indeg[d] + 1;
    }
    if (t == 0) row[NN] = ET;
}

// self-loop in slot 0 of each segment; csr stores BYTE offsets (node*128)
__global__ void k_self(const int* __restrict__ row, int* __restrict__ csr_srcb,
                       float* __restrict__ csr_w){
    int d = blockIdx.x*blockDim.x + threadIdx.x;
    if (d >= NN) return;
    int p = row[d];
    csr_srcb[p] = d << 7;
    csr_w[p] = 0.0f;
}

__global__ void k_scatter(const int* __restrict__ src, const int* __restrict__ dst,
                          const float* __restrict__ deg_out, const int* __restrict__ row,
                          int* __restrict__ cur, int* __restrict__ csr_srcb,
                          float* __restrict__ csr_w){
    int e = blockIdx.x*blockDim.x + threadIdx.x;
    if (e >= EE) return;
    int s = src[e], d = dst[e];
    int pos = row[d] + 1 + atomicAdd(&cur[d], 1);
    csr_srcb[pos] = s << 7;
    float di = deg_out[s] * deg_out[d];
    csr_w[pos] = (di > 0.0f) ? (-__frsqrt_rn(fmaxf(di, 1e-12f))) : 0.0f;
}

// ============ gather SpMV: float2 channels, 4 edge-slots/wave, unroll x4 ============
__global__ void k_spmv_csr(const int* __restrict__ row, const int* __restrict__ csr_srcb,
                           const float* __restrict__ csr_w, const float* __restrict__ v,
                           const float* __restrict__ tprev, float* __restrict__ out, int first){
    int gid = blockIdx.x*blockDim.x + threadIdx.x;
    int node = gid >> 6;
    if (node >= NN) return;
    int lane = gid & 63;
    int slot = lane >> 4;       // 0..3
    int l = lane & 15;          // channel pair index
    const char* vb = (const char*)v + (l << 3);
    int start = row[node] + 1, end = row[node+1];   // skip self-loop slot
    float2 acc = {0.0f, 0.0f};
    int p = start + slot;
    for (; p + 12 < end; p += 16){
        int b0 = csr_srcb[p], b1 = csr_srcb[p+4], b2 = csr_srcb[p+8], b3 = csr_srcb[p+12];
        float w0 = csr_w[p], w1 = csr_w[p+4], w2 = csr_w[p+8], w3 = csr_w[p+12];
        float2 v0 = *(const float2*)(vb + (size_t)(unsigned)b0);
        float2 v1 = *(const float2*)(vb + (size_t)(unsigned)b1);
        float2 v2 = *(const float2*)(vb + (size_t)(unsigned)b2);
        float2 v3 = *(const float2*)(vb + (size_t)(unsigned)b3);
        acc.x += w0*v0.x + w1*v1.x + w2*v2.x + w3*v3.x;
        acc.y += w0*v0.y + w1*v1.y + w2*v2.y + w3*v3.y;
    }
    for (; p < end; p += 4){
        float w0 = csr_w[p];
        float2 v0 = *(const float2*)(vb + (size_t)(unsigned)csr_srcb[p]);
        acc.x += w0*v0.x;
        acc.y += w0*v0.y;
    }
    acc.x += __shfl_xor(acc.x, 32); acc.y += __shfl_xor(acc.y, 32);
    acc.x += DSWZ(acc.x, 0x401F);  acc.y += DSWZ(acc.y, 0x401F);
    if (slot == 0){
        float2 r;
        if (first){
            r = acc;
        } else {
            float2 t = ((const float2*)tprev)[(size_t)node*16 + l];
            r.x = 2.0f*acc.x - t.x;
            r.y = 2.0f*acc.y - t.y;
        }
        ((float2*)out)[(size_t)node*16 + l] = r;
    }
}

// ============ Wg_k = W_k @ G, cbg = cb @ G (tiny) ============
__global__ void k_wg(const float* __restrict__ W, const float* __restrict__ cb,
                     const float* __restrict__ G, float* __restrict__ Wg,
                     float* __restrict__ cbg, int K){
    int t = blockIdx.x*blockDim.x + threadIdx.x;
    if (t < K*2048){
        int k = t >> 11, r = t & 2047;
        int i = r >> 6, j = r & 63;
        float s = 0.0f;
        #pragma unroll 8
        for (int q = 0; q < 32; q++) s += W[k*1024 + i*32 + q] * G[q*64 + j];
        Wg[t] = s;
    } else if (t < K*2048 + 64){
        int j = t - K*2048;
        float s = 0.0f;
        #pragma unroll 8
        for (int q = 0; q < 32; q++) s += cb[q] * G[q*64 + j];
        cbg[j] = s;
    }
}

// ============ H_b = (sum_k T_k @ Wg_k) + cbg; writes interleaved H4 + att dots ============
// H4 layout: [node][lane(64)][block(4)]; attL4/attR4: [node][head(2)][block(4)]
__global__ void k_hfused(const float* __restrict__ T0, const float* __restrict__ T1,
                         const float* __restrict__ T2, const float* __restrict__ T3,
                         const float* __restrict__ T4,
                         const float* __restrict__ Wg, const float* __restrict__ cbg,
                         const float* __restrict__ al, const float* __restrict__ ar,
                         int K, int b, float* __restrict__ H4,
                         float* __restrict__ attL4, float* __restrict__ attR4){
    __shared__ float sW[5*2048];
    for (int i = threadIdx.x; i < K*2048; i += blockDim.x) sW[i] = Wg[i];
    __syncthreads();
    int gid = blockIdx.x*blockDim.x + threadIdx.x;
    int node = gid >> 6;
    if (node >= NN) return;
    int lane = gid & 63;
    int h = lane >> 5, c = lane & 31;
    const float* Ts[5] = {T0, T1, T2, T3, T4};
    float acc = cbg[lane];
    for (int k = 0; k < K; k++){
        float tv = Ts[k][(size_t)node*CCH + c];
        const float* wrow = &sW[k*2048];
        #pragma unroll
        for (int i = 0; i < 32; i++){
            float t = __shfl(tv, i);
            acc += t * wrow[i*64 + lane];
        }
    }
    H4[(size_t)node*256 + lane*4 + b] = acc;
    float va = acc * al[lane];
    float vr = acc * ar[lane];
    RED32(va);
    RED32(vr);
    if (c == 0){
        attL4[(size_t)node*8 + h*4 + b] = va;
        attR4[(size_t)node*8 + h*4 + b] = vr;
    }
}

// ============ fused SuperGAT for ALL 4 blocks, online softmax, 4-edge groups ============
// one wave per dst node; lane = head(1b)|chan(5b); per lane float4 = 4 blocks
__global__ __launch_bounds__(512)
void k_gat4(const int* __restrict__ row, const int* __restrict__ csr_srcb,
            const float* __restrict__ H4,
            const float* __restrict__ attL4, const float* __restrict__ attR4,
            const float* __restrict__ gb0, const float* __restrict__ gb1,
            const float* __restrict__ gb2, const float* __restrict__ gb3,
            float* __restrict__ y4, float* __restrict__ sums){
    int gid = blockIdx.x*blockDim.x + threadIdx.x;
    int node = gid >> 6;
    int lane = gid & 63;
    int wv_ = threadIdx.x >> 6;
    int h = lane >> 5, c = lane & 31;
    const char* Hb = (const char*)H4 + (lane << 4);
    const char* Lb = (const char*)attL4 + (h << 4);
    __shared__ float4 ssum[8*32], ssq[8*32];
    float4 yv = {0.0f, 0.0f, 0.0f, 0.0f};
    if (node < NN){
        float hiA[4], aiA[4], mA[4], denA[4], accA[4];
        {
            float4 t = *(const float4*)&H4[(size_t)node*256 + lane*4];
            hiA[0]=t.x; hiA[1]=t.y; hiA[2]=t.z; hiA[3]=t.w;
            float4 u = *(const float4*)&attR4[(size_t)node*8 + h*4];
            aiA[0]=u.x; aiA[1]=u.y; aiA[2]=u.z; aiA[3]=u.w;
        }
        #pragma unroll
        for (int k = 0; k < 4; k++){ mA[k] = -1e30f; denA[k] = 0.0f; accA[k] = 0.0f; }
        int start = row[node], end = row[node+1];
        int p = start;
        for (; p + 3 < end; p += 4){
            int sb[4]; float hj[4][4], aL[4][4], lg[4][4];
            #pragma unroll
            for (int i = 0; i < 4; i++) sb[i] = csr_srcb[p+i];
            #pragma unroll
            for (int i = 0; i < 4; i++){
                float4 t = *(const float4*)(Hb + ((size_t)(unsigned)sb[i] << 3));
                hj[i][0]=t.x; hj[i][1]=t.y; hj[i][2]=t.z; hj[i][3]=t.w;
                float4 u = *(const float4*)(Lb + (size_t)(unsigned)(sb[i] >> 2));
                aL[i][0]=u.x; aL[i][1]=u.y; aL[i][2]=u.z; aL[i][3]=u.w;
            }
            #pragma unroll
            for (int i = 0; i < 4; i++)
                #pragma unroll
                for (int k = 0; k < 4; k++) lg[i][k] = hiA[k]*hj[i][k];
            #pragma unroll
            for (int i = 0; i < 4; i++)
                #pragma unroll
                for (int k = 0; k < 4; k++) RED32(lg[i][k]);
            #pragma unroll
            for (int k = 0; k < 4; k++){
                float a0 = (aL[0][k] + aiA[k]) * __builtin_amdgcn_rcpf(1.0f + __expf(-lg[0][k]));
                float a1 = (aL[1][k] + aiA[k]) * __builtin_amdgcn_rcpf(1.0f + __expf(-lg[1][k]));
                float a2 = (aL[2][k] + aiA[k]) * __builtin_amdgcn_rcpf(1.0f + __expf(-lg[2][k]));
                float a3 = (aL[3][k] + aiA[k]) * __builtin_amdgcn_rcpf(1.0f + __expf(-lg[3][k]));
                a0 = fmaxf(a0, GNEG*a0);
                a1 = fmaxf(a1, GNEG*a1);
                a2 = fmaxf(a2, GNEG*a2);
                a3 = fmaxf(a3, GNEG*a3);
                float mn = fmaxf(fmaxf(mA[k], fmaxf(a0, a1)), fmaxf(a2, a3));
                float sc = __expf(mA[k] - mn);
                float w0 = __expf(a0 - mn), w1 = __expf(a1 - mn);
                float w2 = __expf(a2 - mn), w3 = __expf(a3 - mn);
                denA[k] = denA[k]*sc + ((w0 + w1) + (w2 + w3));
                accA[k] = accA[k]*sc + (w0*hj[0][k] + w1*hj[1][k]) + (w2*hj[2][k] + w3*hj[3][k]);
                mA[k] = mn;
            }
        }
        for (; p < end; p++){
            int sb0 = csr_srcb[p];
            float hj0[4], aL0[4], lg0[4];
            float4 t = *(const float4*)(Hb + ((size_t)(unsigned)sb0 << 3));
            hj0[0]=t.x; hj0[1]=t.y; hj0[2]=t.z; hj0[3]=t.w;
            float4 u = *(const float4*)(Lb + (size_t)(unsigned)(sb0 >> 2));
            aL0[0]=u.x; aL0[1]=u.y; aL0[2]=u.z; aL0[3]=u.w;
            #pragma unroll
            for (int k = 0; k < 4; k++) lg0[k] = hiA[k]*hj0[k];
            #pragma unroll
            for (int k = 0; k < 4; k++) RED32(lg0[k]);
            #pragma unroll
            for (int k = 0; k < 4; k++){
                float a0 = (aL0[k] + aiA[k]) * __builtin_amdgcn_rcpf(1.0f + __expf(-lg0[k]));
                a0 = fmaxf(a0, GNEG*a0);
                float mn = fmaxf(mA[k], a0);
                float sc = __expf(mA[k] - mn);
                float w0 = __expf(a0 - mn);
                denA[k] = denA[k]*sc + w0;
                accA[k] = accA[k]*sc + w0*hj0[k];
                mA[k] = mn;
            }
        }
        float g[4];
        g[0] = gb0[c]; g[1] = gb1[c]; g[2] = gb2[c]; g[3] = gb3[c];
        float yo[4];
        #pragma unroll
        for (int k = 0; k < 4; k++){
            float accn = accA[k] * __builtin_amdgcn_rcpf(denA[k] + 1e-16f);
            float s_ = 0.5f*(accn + __shfl_xor(accn, 32)) + g[k];
            yo[k] = (s_ > 0.0f) ? 2.0f*s_ : (1.0f + NEGS)*s_;   // leaky(s)+s
        }
        yv.x = yo[0]; yv.y = yo[1]; yv.z = yo[2]; yv.w = yo[3];
        if (h == 0) *(float4*)&y4[(size_t)node*128 + c*4] = yv;
    }
    if (h == 0){
        ssum[wv_*32 + c] = yv;
        float4 q = {yv.x*yv.x, yv.y*yv.y, yv.z*yv.z, yv.w*yv.w};
        ssq[wv_*32 + c] = q;
    }
    __syncthreads();
    if (threadIdx.x < 32){
        float4 s = {0,0,0,0}, q = {0,0,0,0};
        #pragma unroll
        for (int r = 0; r < 8; r++){
            float4 a = ssum[r*32 + threadIdx.x];
            float4 b = ssq[r*32 + threadIdx.x];
            s.x += a.x; s.y += a.y; s.z += a.z; s.w += a.w;
            q.x += b.x; q.y += b.y; q.z += b.z; q.w += b.w;
        }
        atomicAdd(&sums[  0 + threadIdx.x], s.x);
        atomicAdd(&sums[ 32 + threadIdx.x], s.y);
        atomicAdd(&sums[ 64 + threadIdx.x], s.z);
        atomicAdd(&sums[ 96 + threadIdx.x], s.w);
        atomicAdd(&sums[128 + threadIdx.x], q.x);
        atomicAdd(&sums[160 + threadIdx.x], q.y);
        atomicAdd(&sums[192 + threadIdx.x], q.z);
        atomicAdd(&sums[224 + threadIdx.x], q.w);
    }
}

// ============ BN normalize all 4 blocks + sum + final leaky, one pass ============
__global__ void k_norm4(const float* __restrict__ y4, const float* __restrict__ sums,
                        const float* __restrict__ gm0, const float* __restrict__ bt0,
                        const float* __restrict__ gm1, const float* __restrict__ bt1,
                        const float* __restrict__ gm2, const float* __restrict__ bt2,
                        const float* __restrict__ gm3, const float* __restrict__ bt3,
                        float* __restrict__ out){
    int t = blockIdx.x*blockDim.x + threadIdx.x;
    if (t >= NC) return;
    int c = t & 31;
    const float invN = 1.0f / (float)NN;
    float4 v = *(const float4*)&y4[(size_t)t*4];
    float r = 0.0f;
    {
        float mu = sums[c]*invN;       float var = sums[128+c]*invN - mu*mu;
        r += gm0[c]*(v.x - mu)/sqrtf(var + BEPS) + bt0[c];
    }
    {
        float mu = sums[32+c]*invN;    float var = sums[160+c]*invN - mu*mu;
        r += gm1[c]*(v.y - mu)/sqrtf(var + BEPS) + bt1[c];
    }
    {
        float mu = sums[64+c]*invN;    float var = sums[192+c]*invN - mu*mu;
        r += gm2[c]*(v.z - mu)/sqrtf(var + BEPS) + bt2[c];
    }
    {
        float mu = sums[96+c]*invN;    float var = sums[224+c]*invN - mu*mu;
        r += gm3[c]*(v.w - mu)/sqrtf(var + BEPS) + bt3[c];
    }
    out[t] = (r > 0.0f) ? r : NEGS*r;
}

extern "C" void kernel_launch(void* const* d_in, const int* in_sizes, int n_in,
                              void* d_out, int out_size, void* d_ws, size_t ws_size,
                              hipStream_t stream){
    const float* x   = (const float*)d_in[0];
    const int*   ei  = (const int*)d_in[1];
    const int*   src = ei;
    const int*   dst = ei + EE;

    const float *Wp[4], *cbp[4], *Gp[4], *alp[4], *arp[4], *gbp[4], *gmp[4], *btp[4];
    for (int b = 0; b < 4; b++){
        int base = 3 + 8*b;
        Wp[b]  = (const float*)d_in[base+0];
        cbp[b] = (const float*)d_in[base+1];
        Gp[b]  = (const float*)d_in[base+2];
        alp[b] = (const float*)d_in[base+3];
        arp[b] = (const float*)d_in[base+4];
        gbp[b] = (const float*)d_in[base+5];
        gmp[b] = (const float*)d_in[base+6];
        btp[b] = (const float*)d_in[base+7];
    }

    // 16B-aligned workspace carve-up
    char* w8 = (char*)d_ws;
    #define CARVE(ptr_t, name, bytes) ptr_t name = (ptr_t)w8; w8 += (((size_t)(bytes)) + 15) & ~(size_t)15;
    CARVE(float*, deg_out, sizeof(float)*NN)
    CARVE(int*,   indeg,   sizeof(int)*NN)
    CARVE(int*,   cur,     sizeof(int)*NN)
    CARVE(int*,   row,     sizeof(int)*(NN+1))
    CARVE(int*,   csr_srcb, sizeof(int)*ET)
    CARVE(float*, csr_w,   sizeof(float)*ET)
    CARVE(float*, T1,      sizeof(float)*NC)      // T1..T4 contiguous; y4 aliases them later
    CARVE(float*, T2,      sizeof(float)*NC)
    CARVE(float*, T3,      sizeof(float)*NC)
    CARVE(float*, T4,      sizeof(float)*NC)
    CARVE(float*, H4,      sizeof(float)*(size_t)NN*256)
    CARVE(float*, attL4,   sizeof(float)*NN*8)
    CARVE(float*, attR4,   sizeof(float)*NN*8)
    CARVE(float*, Wg,      sizeof(float)*4*5*2048)
    CARVE(float*, cbg,     sizeof(float)*4*64)
    CARVE(float*, sums,    sizeof(float)*256)
    float* y4 = T1;   // T1..T4 are dead after the last k_hfused; y4 = NN*128 floats = their exact span

    float* acc = (float*)d_out;

    const int B = 256;
    const int gE  = (EE + B - 1)/B;
    const int gN  = (NN + B - 1)/B;
    const int gNC = (NC + B - 1)/B;
    const int gW5 = (NN*64 + 511)/512;      // one-wave-per-node @512

    // ---- CSR build ----
    hipMemsetAsync(deg_out, 0, (size_t)3*NN*sizeof(int), stream);  // deg_out, indeg, cur
    k_degs<<<gE, B, 0, stream>>>(src, dst, deg_out, indeg);
    k_scan<<<1, SCAN_T, 0, stream>>>(indeg, row);
    k_self<<<gN, B, 0, stream>>>(row, csr_srcb, csr_w);
    k_scatter<<<gE, B, 0, stream>>>(src, dst, deg_out, row, cur, csr_srcb, csr_w);

    // ---- shared Chebyshev basis ----
    k_spmv_csr<<<gW5, 512, 0, stream>>>(row, csr_srcb, csr_w, x,  (const float*)0, T1, 1);
    k_spmv_csr<<<gW5, 512, 0, stream>>>(row, csr_srcb, csr_w, T1, x,  T2, 0);
    k_spmv_csr<<<gW5, 512, 0, stream>>>(row, csr_srcb, csr_w, T2, T1, T3, 0);
    k_spmv_csr<<<gW5, 512, 0, stream>>>(row, csr_srcb, csr_w, T3, T2, T4, 0);

    // ---- per-block folded weights ----
    const int Ks[4] = {3, 3, 5, 5};
    for (int b = 0; b < 4; b++){
        int tot = Ks[b]*2048 + 64;
        k_wg<<<(tot + B - 1)/B, B, 0, stream>>>(Wp[b], cbp[b], Gp[b],
                                                Wg + b*5*2048, cbg + b*64, Ks[b]);
    }

    // ---- H for all 4 blocks (interleaved layout) ----
    for (int b = 0; b < 4; b++){
        k_hfused<<<gW5, 512, 0, stream>>>(x, T1, T2, T3, T4, Wg + b*5*2048, cbg + b*64,
                                          alp[b], arp[b], Ks[b], b, H4, attL4, attR4);
    }

    // ---- fused SuperGAT over all 4 blocks (y4 overwrites T1..T4 space) ----
    hipMemsetAsync(sums, 0, 256*sizeof(float), stream);
    k_gat4<<<gW5, 512, 0, stream>>>(row, csr_srcb, H4, attL4, attR4,
                                    gbp[0], gbp[1], gbp[2], gbp[3], y4, sums);

    // ---- BN + sum + final leaky, single pass ----
    k_norm4<<<gNC, B, 0, stream>>>(y4, sums,
                                   gmp[0], btp[0], gmp[1], btp[1],
                                   gmp[2], btp[2], gmp[3], btp[3], acc);
}